// Round 2
// baseline (519.751 us; speedup 1.0000x reference)
//
#include <hip/hip_runtime.h>
#include <hip/hip_bf16.h>
#include <math.h>

#define N_TOK 2048
#define DIM   1024
#define NE    16
#define NH    2048
#define NO    1024

typedef __attribute__((ext_vector_type(8))) short short8;
typedef __attribute__((ext_vector_type(4))) float f32x4;

__device__ __forceinline__ unsigned short f2bf(float f) {
  union { float f; unsigned u; } v; v.f = f;
  unsigned r = v.u + 0x7FFFu + ((v.u >> 16) & 1u);  // RNE
  return (unsigned short)(r >> 16);
}

__device__ __forceinline__ short8 pack8(float4 a, float4 b) {
  short8 r;
  r[0] = (short)f2bf(a.x); r[1] = (short)f2bf(a.y);
  r[2] = (short)f2bf(a.z); r[3] = (short)f2bf(a.w);
  r[4] = (short)f2bf(b.x); r[5] = (short)f2bf(b.y);
  r[6] = (short)f2bf(b.z); r[7] = (short)f2bf(b.w);
  return r;
}

__device__ __forceinline__ unsigned pkbf(float x, float y) {
  float2 f; f.x = x; f.y = y;
  __hip_bfloat162 b = __float22bfloat162_rn(f);     // v_cvt_pk_bf16_f32 (RNE)
  unsigned u; __builtin_memcpy(&u, &b, 4);
  return u;
}
__device__ __forceinline__ short8 cvt8(float4 a, float4 b) {
  union { short8 s; unsigned u[4]; } r;
  r.u[0] = pkbf(a.x, a.y); r.u[1] = pkbf(a.z, a.w);
  r.u[2] = pkbf(b.x, b.y); r.u[3] = pkbf(b.z, b.w);
  return r.s;
}

// async global->LDS, 16B/lane; LDS dest = wave-uniform base + lane*16 (m97/m104)
__device__ __forceinline__ void glds16(const void* g, void* l) {
  __builtin_amdgcn_global_load_lds(
      (const __attribute__((address_space(1))) void*)g,
      (__attribute__((address_space(3))) void*)l, 16, 0, 0);
}

// ---------------- Router: fp32 in, double accum, top-2 + renorm ----------------
__global__ __launch_bounds__(256) void router_kernel(
    const float* __restrict__ z, const float* __restrict__ rw,
    const float* __restrict__ rb, int* __restrict__ counts,
    int* __restrict__ list, float* __restrict__ tkw) {
  const int n = blockIdx.x;
  const int t = threadIdx.x;
  const int e = t >> 4, sub = t & 15;
  const float* zr = z + (size_t)n * DIM;
  const float* wr = rw + (size_t)e * DIM;
  double acc = 0.0;
#pragma unroll
  for (int i = 0; i < 16; ++i) {
    const int d = i * 64 + sub * 4;
    const float4 zv = *(const float4*)(zr + d);
    const float4 wv = *(const float4*)(wr + d);
    acc += (double)zv.x * wv.x + (double)zv.y * wv.y
         + (double)zv.z * wv.z + (double)zv.w * wv.w;
  }
  acc += __shfl_xor(acc, 8, 16);
  acc += __shfl_xor(acc, 4, 16);
  acc += __shfl_xor(acc, 2, 16);
  acc += __shfl_xor(acc, 1, 16);
  __shared__ double logits[NE];
  if (sub == 0) logits[e] = acc + (double)rb[e];
  __syncthreads();
  if (t == 0) {
    int i0 = -1, i1 = -1; double v0 = -1e300, v1 = -1e300;
    for (int i = 0; i < NE; ++i) {
      const double v = logits[i];
      if (v > v0) { v1 = v0; i1 = i0; v0 = v; i0 = i; }
      else if (v > v1) { v1 = v; i1 = i; }
    }
    const double w0 = 1.0 / (1.0 + exp(v1 - v0));
    tkw[n * 2 + 0] = (float)w0;
    tkw[n * 2 + 1] = (float)(1.0 - w0);
    const int p0 = atomicAdd(&counts[i0], 1); list[i0 * N_TOK + p0] = n * 2;
    const int p1 = atomicAdd(&counts[i1], 1); list[i1 * N_TOK + p1] = n * 2 + 1;
  }
}

// ---------------- z -> bf16 (once per call) ----------------
__global__ __launch_bounds__(256) void convert_z_kernel(
    const float* __restrict__ z, unsigned short* __restrict__ zbf) {
  const int i = (blockIdx.x * 256 + threadIdx.x) * 8;
  const float4 a = *(const float4*)(z + i);
  const float4 b = *(const float4*)(z + i + 4);
  *(short8*)(zbf + i) = pack8(a, b);
}

#define BM 128
#define BK 64
#define NT1 (DIM / BK)     // 16
#define NT2 (NH / BK)      // 32
#define ASZ (BM * BK * 2)  // 16 KB bf16 A tile
#define BN1 128
#define BN2 64
#define MT_LEVELS 8
#define GRID_GEMM (MT_LEVELS * NE * 16)   // both gemms: 16 nt-tiles

// Expert-locked XCD map: bid%8 == e%8 -> all blocks of one expert share an XCD:
// mt-pair weight panels merge in that L2, and the expert's token/h slice stays
// resident there. bid = ((mt*32 + nt*2 + eHi) << 3) | xcd  (bijective over 2048).
__device__ __forceinline__ void decode_bid_xcd(int bid, int& mt, int& e, int& nt) {
  const int slot = bid >> 3;
  mt = slot >> 5;
  const int rem = slot & 31;
  e = (bid & 7) + ((rem & 1) << 3);
  nt = rem >> 1;
}

// ---------------- GEMM1: h[slot] = gelu(zbf[tok] @ w1[e]^T + b1[e]) -> bf16 ----
// A (tokens, bf16) via glds16 double-buffer; B (weights, fp32) global->reg->cvt,
// never in LDS. Counted vmcnt(16) + raw s_barrier: B loads stay in flight
// across the barrier (T4); only the 4 glds16 are drained.
__global__ __launch_bounds__(256, 2) void gemm1_kernel(
    const unsigned short* __restrict__ zbf, const float* __restrict__ w1,
    const float* __restrict__ b1, const int* __restrict__ counts,
    const int* __restrict__ list, unsigned short* __restrict__ h) {
  int mt, e, nt;
  decode_bid_xcd(blockIdx.x, mt, e, nt);
  const int ne = counts[e];
  if (mt * BM >= ne) return;
  const int t = threadIdx.x;

  __shared__ __align__(16) unsigned char As[2 * ASZ];   // 32 KB
  __shared__ int ent_s[BM];
  if (t < BM) {
    const int idx = mt * BM + t;
    ent_s[t] = (idx < ne) ? list[e * N_TOK + idx] : -1;
  }
  __syncthreads();

  const int lane = t & 63, w = t >> 6;
  const unsigned short* aP[4];
  unsigned char* aL[4];
  {
    const int l3 = lane >> 3, c7 = lane & 7;
#pragma unroll
    for (int p = 0; p < 4; ++p) {
      const int CI = w + 4 * p;
      const int R = 8 * CI + l3;
      const int c = c7 ^ (R & 7);
      const int en = ent_s[R];
      aP[p] = zbf + (size_t)(en >= 0 ? (en >> 1) : 0) * DIM + c * 8;
      aL[p] = As + CI * 1024;
    }
  }
  const int wm = (w & 1) * 64, wn = (w >> 1) * 64;
  const int l15 = lane & 15, quad = lane >> 4;

  // B fragment rows: lane holds col (l&15), k = quad*8..+8 -> direct from w1.
  const float* bRow[4];
#pragma unroll
  for (int j = 0; j < 4; ++j)
    bRow[j] = w1 + ((size_t)e * NH + (size_t)(nt * BN1 + wn + j * 16 + l15)) * DIM + quad * 8;

  f32x4 acc[4][4];
#pragma unroll
  for (int i = 0; i < 4; ++i)
#pragma unroll
    for (int j = 0; j < 4; ++j) acc[i][j] = (f32x4){0.f, 0.f, 0.f, 0.f};

  float4 breg[16];
  // prologue: tile 0
#pragma unroll
  for (int p = 0; p < 4; ++p) glds16(aP[p], aL[p]);
  __builtin_amdgcn_sched_barrier(0);
#pragma unroll
  for (int j = 0; j < 4; ++j)
#pragma unroll
    for (int s = 0; s < 2; ++s) {
      breg[(j * 2 + s) * 2 + 0] = *(const float4*)(bRow[j] + s * 32);
      breg[(j * 2 + s) * 2 + 1] = *(const float4*)(bRow[j] + s * 32 + 4);
    }
  __builtin_amdgcn_sched_barrier(0);
  asm volatile("s_waitcnt vmcnt(16)" ::: "memory");   // glds16 done; B in flight
  __builtin_amdgcn_s_barrier();

#pragma unroll 2
  for (int kt = 0; kt < NT1; ++kt) {
    const int cur = kt & 1, nxt = cur ^ 1;
    short8 bfr[2][4];
#pragma unroll
    for (int j = 0; j < 4; ++j)
#pragma unroll
      for (int s = 0; s < 2; ++s)
        bfr[s][j] = cvt8(breg[(j * 2 + s) * 2 + 0], breg[(j * 2 + s) * 2 + 1]);
    if (kt + 1 < NT1) {
      const int k1 = (kt + 1) * BK;
#pragma unroll
      for (int p = 0; p < 4; ++p) glds16(aP[p] + k1, aL[p] + nxt * ASZ);
      __builtin_amdgcn_sched_barrier(0);   // pin: glds16 older than B loads
#pragma unroll
      for (int j = 0; j < 4; ++j)
#pragma unroll
        for (int s = 0; s < 2; ++s) {
          breg[(j * 2 + s) * 2 + 0] = *(const float4*)(bRow[j] + k1 + s * 32);
          breg[(j * 2 + s) * 2 + 1] = *(const float4*)(bRow[j] + k1 + s * 32 + 4);
        }
      __builtin_amdgcn_sched_barrier(0);   // pin: loads issued before compute
    }
    const unsigned char* Ac = As + cur * ASZ;
#pragma unroll
    for (int s = 0; s < 2; ++s) {
      short8 af[4];
      const int c0 = s * 4 + quad;
#pragma unroll
      for (int i = 0; i < 4; ++i) {
        const int R = wm + i * 16 + l15;
        af[i] = *(const short8*)(Ac + R * 128 + ((c0 ^ (R & 7)) << 4));
      }
#pragma unroll
      for (int i = 0; i < 4; ++i)
#pragma unroll
        for (int j = 0; j < 4; ++j)
          acc[i][j] = __builtin_amdgcn_mfma_f32_16x16x32_bf16(af[i], bfr[s][j], acc[i][j], 0, 0, 0);
    }
    if (kt + 1 < NT1) {
      asm volatile("s_waitcnt vmcnt(16)" ::: "memory");  // own glds16 retired
      __builtin_amdgcn_s_barrier();                      // A(kt+1) visible to all
    }
  }

  const int r4 = quad * 4;    // C/D: col=lane&15, row=quad*4+reg
#pragma unroll
  for (int i = 0; i < 4; ++i) {
#pragma unroll
    for (int reg = 0; reg < 4; ++reg) {
      const int row = wm + i * 16 + r4 + reg;
      const int en = ent_s[row];
      if (en < 0) continue;
      unsigned short* hrow = h + (size_t)en * NH;
#pragma unroll
      for (int j = 0; j < 4; ++j) {
        const int col = nt * BN1 + wn + j * 16 + l15;
        float v = acc[i][j][reg] + b1[e * NH + col];
        v = 0.5f * v * (1.0f + erff(v * 0.70710678118654752f));
        hrow[col] = f2bf(v);
      }
    }
  }
}

// ---------------- GEMM2: contrib[slot] = h[slot] @ w2[e]^T + b2[e] (fp32) -----
// Same structure; BN=64 (16 nt-tiles -> 512 active blocks, 2/CU) and lighter
// registers (target 3 blocks/CU).
__global__ __launch_bounds__(256, 3) void gemm2_kernel(
    const unsigned short* __restrict__ h, const float* __restrict__ w2,
    const float* __restrict__ b2, const int* __restrict__ counts,
    const int* __restrict__ list, float* __restrict__ contrib) {
  int mt, e, nt;
  decode_bid_xcd(blockIdx.x, mt, e, nt);
  const int ne = counts[e];
  if (mt * BM >= ne) return;
  const int t = threadIdx.x;

  __shared__ __align__(16) unsigned char As[2 * ASZ];   // 32 KB
  __shared__ int ent_s[BM];
  if (t < BM) {
    const int idx = mt * BM + t;
    ent_s[t] = (idx < ne) ? list[e * N_TOK + idx] : -1;
  }
  __syncthreads();

  const int lane = t & 63, w = t >> 6;
  const unsigned short* aP[4];
  unsigned char* aL[4];
  {
    const int l3 = lane >> 3, c7 = lane & 7;
#pragma unroll
    for (int p = 0; p < 4; ++p) {
      const int CI = w + 4 * p;
      const int R = 8 * CI + l3;
      const int c = c7 ^ (R & 7);
      const int en = ent_s[R];
      aP[p] = h + (size_t)(en >= 0 ? en : 0) * NH + c * 8;
      aL[p] = As + CI * 1024;
    }
  }
  const int wm = (w & 1) * 64, wn = (w >> 1) * 32;
  const int l15 = lane & 15, quad = lane >> 4;

  const float* bRow[2];
#pragma unroll
  for (int j = 0; j < 2; ++j)
    bRow[j] = w2 + ((size_t)e * NO + (size_t)(nt * BN2 + wn + j * 16 + l15)) * NH + quad * 8;

  f32x4 acc[4][2];
#pragma unroll
  for (int i = 0; i < 4; ++i)
#pragma unroll
    for (int j = 0; j < 2; ++j) acc[i][j] = (f32x4){0.f, 0.f, 0.f, 0.f};

  float4 breg[8];
#pragma unroll
  for (int p = 0; p < 4; ++p) glds16(aP[p], aL[p]);
  __builtin_amdgcn_sched_barrier(0);
#pragma unroll
  for (int j = 0; j < 2; ++j)
#pragma unroll
    for (int s = 0; s < 2; ++s) {
      breg[(j * 2 + s) * 2 + 0] = *(const float4*)(bRow[j] + s * 32);
      breg[(j * 2 + s) * 2 + 1] = *(const float4*)(bRow[j] + s * 32 + 4);
    }
  __builtin_amdgcn_sched_barrier(0);
  asm volatile("s_waitcnt vmcnt(8)" ::: "memory");
  __builtin_amdgcn_s_barrier();

#pragma unroll 2
  for (int kt = 0; kt < NT2; ++kt) {
    const int cur = kt & 1, nxt = cur ^ 1;
    short8 bfr[2][2];
#pragma unroll
    for (int j = 0; j < 2; ++j)
#pragma unroll
      for (int s = 0; s < 2; ++s)
        bfr[s][j] = cvt8(breg[(j * 2 + s) * 2 + 0], breg[(j * 2 + s) * 2 + 1]);
    if (kt + 1 < NT2) {
      const int k1 = (kt + 1) * BK;
#pragma unroll
      for (int p = 0; p < 4; ++p) glds16(aP[p] + k1, aL[p] + nxt * ASZ);
      __builtin_amdgcn_sched_barrier(0);
#pragma unroll
      for (int j = 0; j < 2; ++j)
#pragma unroll
        for (int s = 0; s < 2; ++s) {
          breg[(j * 2 + s) * 2 + 0] = *(const float4*)(bRow[j] + k1 + s * 32);
          breg[(j * 2 + s) * 2 + 1] = *(const float4*)(bRow[j] + k1 + s * 32 + 4);
        }
      __builtin_amdgcn_sched_barrier(0);
    }
    const unsigned char* Ac = As + cur * ASZ;
#pragma unroll
    for (int s = 0; s < 2; ++s) {
      short8 af[4];
      const int c0 = s * 4 + quad;
#pragma unroll
      for (int i = 0; i < 4; ++i) {
        const int R = wm + i * 16 + l15;
        af[i] = *(const short8*)(Ac + R * 128 + ((c0 ^ (R & 7)) << 4));
      }
#pragma unroll
      for (int i = 0; i < 4; ++i)
#pragma unroll
        for (int j = 0; j < 2; ++j)
          acc[i][j] = __builtin_amdgcn_mfma_f32_16x16x32_bf16(af[i], bfr[s][j], acc[i][j], 0, 0, 0);
    }
    if (kt + 1 < NT2) {
      asm volatile("s_waitcnt vmcnt(8)" ::: "memory");
      __builtin_amdgcn_s_barrier();
    }
  }

  const int r4 = quad * 4;
#pragma unroll
  for (int i = 0; i < 4; ++i) {
#pragma unroll
    for (int reg = 0; reg < 4; ++reg) {
      const int row = wm + i * 16 + r4 + reg;
      const int en = ent_s[row];
      if (en < 0) continue;
      float* crow = contrib + (size_t)en * NO;
#pragma unroll
      for (int j = 0; j < 2; ++j) {
        const int col = nt * BN2 + wn + j * 16 + l15;
        crow[col] = acc[i][j][reg] + b2[e * NO + col];
      }
    }
  }
}

// ---------------- Combine ----------------
__global__ __launch_bounds__(256) void combine_kernel(
    const float* __restrict__ contrib, const float* __restrict__ tkw,
    float* __restrict__ out) {
  const int gid = blockIdx.x * 256 + threadIdx.x;
  const int n = gid >> 8;
  const int c = (gid & 255) * 4;
  const float w0 = tkw[n * 2], w1 = tkw[n * 2 + 1];
  const float4 a = *(const float4*)(contrib + (size_t)(n * 2) * NO + c);
  const float4 b = *(const float4*)(contrib + (size_t)(n * 2 + 1) * NO + c);
  float4 o;
  o.x = w0 * a.x + w1 * b.x; o.y = w0 * a.y + w1 * b.y;
  o.z = w0 * a.z + w1 * b.z; o.w = w0 * a.w + w1 * b.w;
  *(float4*)(out + (size_t)n * NO + c) = o;
}

extern "C" void kernel_launch(void* const* d_in, const int* in_sizes, int n_in,
                              void* d_out, int out_size, void* d_ws, size_t ws_size,
                              hipStream_t stream) {
  const float* z  = (const float*)d_in[0];
  const float* rw = (const float*)d_in[1];
  const float* rb = (const float*)d_in[2];
  const float* w1 = (const float*)d_in[3];
  const float* b1 = (const float*)d_in[4];
  const float* w2 = (const float*)d_in[5];
  const float* b2 = (const float*)d_in[6];
  float* out = (float*)d_out;

  char* ws = (char*)d_ws;
  int*   counts = (int*)ws;                                    // 256 B
  int*   list   = (int*)(ws + 256);                            // 128 KB
  float* tkw    = (float*)(ws + 256 + 131072);                 // 16 KB
  unsigned short* zbf = (unsigned short*)(ws + 262144);        // 4 MB
  unsigned short* h = (unsigned short*)(ws + 262144 + 4194304);        // 16 MB
  float* contrib = (float*)(ws + 262144 + 4194304 + 16777216);         // 16 MB

  hipMemsetAsync(counts, 0, NE * sizeof(int), stream);
  convert_z_kernel<<<(N_TOK * DIM / 8) / 256, 256, 0, stream>>>(z, zbf);
  router_kernel<<<N_TOK, 256, 0, stream>>>(z, rw, rb, counts, list, tkw);
  gemm1_kernel<<<GRID_GEMM, 256, 0, stream>>>(zbf, w1, b1, counts, list, h);
  gemm2_kernel<<<GRID_GEMM, 256, 0, stream>>>(h, w2, b2, counts, list, contrib);
  combine_kernel<<<(N_TOK * (NO / 4)) / 256, 256, 0, stream>>>(contrib, tkw, out);
}

// Round 3
// 478.543 us; speedup vs baseline: 1.0861x; 1.0861x over previous
//
#include <hip/hip_runtime.h>
#include <hip/hip_bf16.h>
#include <math.h>

#define N_TOK 2048
#define DIM   1024
#define NE    16
#define NH    2048
#define NO    1024

typedef __attribute__((ext_vector_type(8))) short short8;
typedef __attribute__((ext_vector_type(4))) float f32x4;

__device__ __forceinline__ unsigned short f2bf(float f) {
  union { float f; unsigned u; } v; v.f = f;
  unsigned r = v.u + 0x7FFFu + ((v.u >> 16) & 1u);  // RNE
  return (unsigned short)(r >> 16);
}

__device__ __forceinline__ short8 pack8(float4 a, float4 b) {
  short8 r;
  r[0] = (short)f2bf(a.x); r[1] = (short)f2bf(a.y);
  r[2] = (short)f2bf(a.z); r[3] = (short)f2bf(a.w);
  r[4] = (short)f2bf(b.x); r[5] = (short)f2bf(b.y);
  r[6] = (short)f2bf(b.z); r[7] = (short)f2bf(b.w);
  return r;
}

__device__ __forceinline__ unsigned pkbf(float x, float y) {
  float2 f; f.x = x; f.y = y;
  __hip_bfloat162 b = __float22bfloat162_rn(f);     // v_cvt_pk_bf16_f32 (RNE)
  unsigned u; __builtin_memcpy(&u, &b, 4);
  return u;
}
__device__ __forceinline__ short8 cvt8(float4 a, float4 b) {
  union { short8 s; unsigned u[4]; } r;
  r.u[0] = pkbf(a.x, a.y); r.u[1] = pkbf(a.z, a.w);
  r.u[2] = pkbf(b.x, b.y); r.u[3] = pkbf(b.z, b.w);
  return r.s;
}

// async global->LDS, 16B/lane; LDS dest = wave-uniform base + lane*16 (m97/m104)
__device__ __forceinline__ void glds16(const void* g, void* l) {
  __builtin_amdgcn_global_load_lds(
      (const __attribute__((address_space(1))) void*)g,
      (__attribute__((address_space(3))) void*)l, 16, 0, 0);
}

// LDS-only barrier (lgkmcnt(0), vmcnt untouched) for the WAR edge after MFMA.
__device__ __forceinline__ void lds_barrier() {
  __builtin_amdgcn_s_waitcnt(0xC07F);
  __builtin_amdgcn_s_barrier();
}

// ---------------- Router: fp32 in, double accum, top-2 + renorm ----------------
__global__ __launch_bounds__(256) void router_kernel(
    const float* __restrict__ z, const float* __restrict__ rw,
    const float* __restrict__ rb, int* __restrict__ counts,
    int* __restrict__ list, float* __restrict__ tkw) {
  const int n = blockIdx.x;
  const int t = threadIdx.x;
  const int e = t >> 4, sub = t & 15;
  const float* zr = z + (size_t)n * DIM;
  const float* wr = rw + (size_t)e * DIM;
  double acc = 0.0;
#pragma unroll
  for (int i = 0; i < 16; ++i) {
    const int d = i * 64 + sub * 4;
    const float4 zv = *(const float4*)(zr + d);
    const float4 wv = *(const float4*)(wr + d);
    acc += (double)zv.x * wv.x + (double)zv.y * wv.y
         + (double)zv.z * wv.z + (double)zv.w * wv.w;
  }
  acc += __shfl_xor(acc, 8, 16);
  acc += __shfl_xor(acc, 4, 16);
  acc += __shfl_xor(acc, 2, 16);
  acc += __shfl_xor(acc, 1, 16);
  __shared__ double logits[NE];
  if (sub == 0) logits[e] = acc + (double)rb[e];
  __syncthreads();
  if (t == 0) {
    int i0 = -1, i1 = -1; double v0 = -1e300, v1 = -1e300;
    for (int i = 0; i < NE; ++i) {
      const double v = logits[i];
      if (v > v0) { v1 = v0; i1 = i0; v0 = v; i0 = i; }
      else if (v > v1) { v1 = v; i1 = i; }
    }
    const double w0 = 1.0 / (1.0 + exp(v1 - v0));
    tkw[n * 2 + 0] = (float)w0;
    tkw[n * 2 + 1] = (float)(1.0 - w0);
    const int p0 = atomicAdd(&counts[i0], 1); list[i0 * N_TOK + p0] = n * 2;
    const int p1 = atomicAdd(&counts[i1], 1); list[i1 * N_TOK + p1] = n * 2 + 1;
  }
}

// ---------------- z -> bf16 (once per call) ----------------
__global__ __launch_bounds__(256) void convert_z_kernel(
    const float* __restrict__ z, unsigned short* __restrict__ zbf) {
  const int i = (blockIdx.x * 256 + threadIdx.x) * 8;
  const float4 a = *(const float4*)(z + i);
  const float4 b = *(const float4*)(z + i + 4);
  *(short8*)(zbf + i) = pack8(a, b);
}

#define BM 64
#define BK 64
#define BN1 128
#define BN2 64
#define NT1 (DIM / BK)     // 16 K-steps (gemm1)
#define NT2 (NH / BK)      // 32 K-steps (gemm2)
#define MT_LEVELS 16       // covers up to 1024 tokens/expert (same cap as before)
#define GRID_G 4096        // 16 nt * 16 mt * 16 e, xcd-interleaved

// Expert-locked XCD decode: e%8 == bid%8 (all of expert e's blocks and both
// gemms' h traffic pin to XCD e%8); mt varies fastest within an XCD so the
// ~4 active mt replicas of a weight panel are L2-merged.
// bid = (((nt*16 + mt)*2 + eHi) << 3) | xcd
__device__ __forceinline__ void decode_bid_xcd(int bid, int& mt, int& e, int& nt) {
  const int slot = bid >> 3;
  e = (bid & 7) + ((slot & 1) << 3);
  mt = (slot >> 1) & 15;
  nt = slot >> 5;
}

// ---------------- GEMM1: h[slot] = gelu(zbf[tok] @ w1[e]^T + b1[e]) -> bf16 ----
// r0-proven 2-barrier glds16 structure; BM=64 doubles active blocks (4/CU,
// 3 resident by LDS) vs the 128-row tile's 2/CU.
__global__ __launch_bounds__(256, 3) void gemm1_kernel(
    const unsigned short* __restrict__ zbf, const float* __restrict__ w1,
    const float* __restrict__ b1, const int* __restrict__ counts,
    const int* __restrict__ list, unsigned short* __restrict__ h) {
  int mt, e, nt;
  decode_bid_xcd(blockIdx.x, mt, e, nt);
  const int ne = counts[e];
  if (mt * BM >= ne) return;
  const int t = threadIdx.x;

  __shared__ __align__(16) unsigned char As[BM * BK * 2];   // 8 KB bf16
  __shared__ __align__(16) unsigned char Bs[BN1 * BK * 4];  // 32 KB fp32
  __shared__ int ent_s[BM];
  if (t < BM) {
    const int idx = mt * BM + t;
    ent_s[t] = (idx < ne) ? list[e * N_TOK + idx] : -1;
  }
  __syncthreads();

  const int lane = t & 63, w = t >> 6;
  // A: 8 chunks of 1KB (2/wave). B: 32 chunks (8/wave).
  const unsigned short* aP[2];
  const float* bP[8];
  unsigned char *aL[2], *bL[8];
  {
    const int l3 = lane >> 3, c7 = lane & 7;
#pragma unroll
    for (int p = 0; p < 2; ++p) {
      const int CI = w + 4 * p;
      const int R = 8 * CI + l3;
      const int c = c7 ^ (R & 7);
      const int en = ent_s[R];
      aP[p] = zbf + (size_t)(en >= 0 ? (en >> 1) : 0) * DIM + c * 8;
      aL[p] = As + CI * 1024;
    }
    const int l4 = lane >> 4, c15 = lane & 15;
    const float* bbase = w1 + ((size_t)e * NH + (size_t)nt * BN1) * DIM;
#pragma unroll
    for (int q = 0; q < 8; ++q) {
      const int CI = w + 4 * q;
      const int R = 4 * CI + l4;
      const int c = c15 ^ (R & 15);
      bP[q] = bbase + (size_t)R * DIM + c * 4;
      bL[q] = Bs + CI * 1024;
    }
  }

  const int wm = (w & 1) * 32, wn = (w >> 1) * 64;
  const int l15 = lane & 15, quad = lane >> 4;

  f32x4 acc[2][4];
#pragma unroll
  for (int i = 0; i < 2; ++i)
#pragma unroll
    for (int j = 0; j < 4; ++j) acc[i][j] = (f32x4){0.f, 0.f, 0.f, 0.f};

  for (int k0 = 0; k0 < DIM; k0 += BK) {
#pragma unroll
    for (int p = 0; p < 2; ++p) glds16(aP[p] + k0, aL[p]);
#pragma unroll
    for (int q = 0; q < 8; ++q) glds16(bP[q] + k0, bL[q]);
    __syncthreads();          // vmcnt(0) drain -> LDS filled (m97 structure)
#pragma unroll
    for (int kk = 0; kk < BK; kk += 32) {
      short8 af[2], bfr[4];
#pragma unroll
      for (int i = 0; i < 2; ++i) {
        const int R = wm + i * 16 + l15;
        const int c0 = (kk >> 3) + quad;
        af[i] = *(const short8*)(As + R * 128 + ((c0 ^ (R & 7)) << 4));
      }
#pragma unroll
      for (int j = 0; j < 4; ++j) {
        const int R = wn + j * 16 + l15;
        const int c0 = (kk >> 2) + 2 * quad;
        const float4 f0 = *(const float4*)(Bs + R * 256 + ((c0 ^ (R & 15)) << 4));
        const float4 f1 = *(const float4*)(Bs + R * 256 + (((c0 + 1) ^ (R & 15)) << 4));
        bfr[j] = cvt8(f0, f1);
      }
#pragma unroll
      for (int i = 0; i < 2; ++i)
#pragma unroll
        for (int j = 0; j < 4; ++j)
          acc[i][j] = __builtin_amdgcn_mfma_f32_16x16x32_bf16(af[i], bfr[j], acc[i][j], 0, 0, 0);
    }
    lds_barrier();            // readers done before next fill (WAR)
  }

  const int r4 = quad * 4;    // C/D: col=lane&15, row=quad*4+reg
#pragma unroll
  for (int i = 0; i < 2; ++i) {
#pragma unroll
    for (int reg = 0; reg < 4; ++reg) {
      const int row = wm + i * 16 + r4 + reg;
      const int en = ent_s[row];
      if (en < 0) continue;
      unsigned short* hrow = h + (size_t)en * NH;
#pragma unroll
      for (int j = 0; j < 4; ++j) {
        const int col = nt * BN1 + wn + j * 16 + l15;
        float v = acc[i][j][reg] + b1[e * NH + col];
        v = 0.5f * v * (1.0f + erff(v * 0.70710678118654752f));
        hrow[col] = f2bf(v);
      }
    }
  }
}

// ---------------- GEMM2 (+fused combine): out[n] += tkw[slot]*(h@w2^T + b2) ----
// BM=64, BN=64 -> ~2048 active blocks (4/CU resident, 16 waves/CU).
__global__ __launch_bounds__(256, 4) void gemm2_kernel(
    const unsigned short* __restrict__ h, const float* __restrict__ w2,
    const float* __restrict__ b2, const int* __restrict__ counts,
    const int* __restrict__ list, const float* __restrict__ tkw,
    float* __restrict__ out) {
  int mt, e, nt;
  decode_bid_xcd(blockIdx.x, mt, e, nt);
  const int ne = counts[e];
  if (mt * BM >= ne) return;
  const int t = threadIdx.x;

  __shared__ __align__(16) unsigned char As[BM * BK * 2];   // 8 KB bf16
  __shared__ __align__(16) unsigned char Bs[BN2 * BK * 4];  // 16 KB fp32
  __shared__ int ent_s[BM];
  if (t < BM) {
    const int idx = mt * BM + t;
    ent_s[t] = (idx < ne) ? list[e * N_TOK + idx] : -1;
  }
  __syncthreads();

  const int lane = t & 63, w = t >> 6;
  const unsigned short* aP[2];
  const float* bP[4];
  unsigned char *aL[2], *bL[4];
  {
    const int l3 = lane >> 3, c7 = lane & 7;
#pragma unroll
    for (int p = 0; p < 2; ++p) {
      const int CI = w + 4 * p;
      const int R = 8 * CI + l3;
      const int c = c7 ^ (R & 7);
      const int en = ent_s[R];
      aP[p] = h + (size_t)(en >= 0 ? en : 0) * NH + c * 8;
      aL[p] = As + CI * 1024;
    }
    const int l4 = lane >> 4, c15 = lane & 15;
    const float* bbase = w2 + ((size_t)e * NO + (size_t)nt * BN2) * NH;
#pragma unroll
    for (int q = 0; q < 4; ++q) {
      const int CI = w + 4 * q;
      const int R = 4 * CI + l4;
      const int c = c15 ^ (R & 15);
      bP[q] = bbase + (size_t)R * NH + c * 4;
      bL[q] = Bs + CI * 1024;
    }
  }

  const int wm = (w & 1) * 32, wn = (w >> 1) * 32;
  const int l15 = lane & 15, quad = lane >> 4;

  f32x4 acc[2][2];
#pragma unroll
  for (int i = 0; i < 2; ++i)
#pragma unroll
    for (int j = 0; j < 2; ++j) acc[i][j] = (f32x4){0.f, 0.f, 0.f, 0.f};

  for (int k0 = 0; k0 < NH; k0 += BK) {
#pragma unroll
    for (int p = 0; p < 2; ++p) glds16(aP[p] + k0, aL[p]);
#pragma unroll
    for (int q = 0; q < 4; ++q) glds16(bP[q] + k0, bL[q]);
    __syncthreads();
#pragma unroll
    for (int kk = 0; kk < BK; kk += 32) {
      short8 af[2], bfr[2];
#pragma unroll
      for (int i = 0; i < 2; ++i) {
        const int R = wm + i * 16 + l15;
        const int c0 = (kk >> 3) + quad;
        af[i] = *(const short8*)(As + R * 128 + ((c0 ^ (R & 7)) << 4));
      }
#pragma unroll
      for (int j = 0; j < 2; ++j) {
        const int R = wn + j * 16 + l15;
        const int c0 = (kk >> 2) + 2 * quad;
        const float4 f0 = *(const float4*)(Bs + R * 256 + ((c0 ^ (R & 15)) << 4));
        const float4 f1 = *(const float4*)(Bs + R * 256 + (((c0 + 1) ^ (R & 15)) << 4));
        bfr[j] = cvt8(f0, f1);
      }
#pragma unroll
      for (int i = 0; i < 2; ++i)
#pragma unroll
        for (int j = 0; j < 2; ++j)
          acc[i][j] = __builtin_amdgcn_mfma_f32_16x16x32_bf16(af[i], bfr[j], acc[i][j], 0, 0, 0);
    }
    lds_barrier();
  }

  const int r4 = quad * 4;
#pragma unroll
  for (int i = 0; i < 2; ++i) {
#pragma unroll
    for (int reg = 0; reg < 4; ++reg) {
      const int row = wm + i * 16 + r4 + reg;
      const int en = ent_s[row];
      if (en < 0) continue;
      const float wgt = tkw[en];
      float* orow = out + (size_t)(en >> 1) * NO;
#pragma unroll
      for (int j = 0; j < 2; ++j) {
        const int col = nt * BN2 + wn + j * 16 + l15;
        atomicAdd(&orow[col], wgt * (acc[i][j][reg] + b2[e * NO + col]));
      }
    }
  }
}

extern "C" void kernel_launch(void* const* d_in, const int* in_sizes, int n_in,
                              void* d_out, int out_size, void* d_ws, size_t ws_size,
                              hipStream_t stream) {
  const float* z  = (const float*)d_in[0];
  const float* rw = (const float*)d_in[1];
  const float* rb = (const float*)d_in[2];
  const float* w1 = (const float*)d_in[3];
  const float* b1 = (const float*)d_in[4];
  const float* w2 = (const float*)d_in[5];
  const float* b2 = (const float*)d_in[6];
  float* out = (float*)d_out;

  char* ws = (char*)d_ws;
  int*   counts = (int*)ws;                                    // 256 B
  int*   list   = (int*)(ws + 256);                            // 128 KB
  float* tkw    = (float*)(ws + 256 + 131072);                 // 16 KB
  unsigned short* zbf = (unsigned short*)(ws + 262144);        // 4 MB
  unsigned short* h = (unsigned short*)(ws + 262144 + 4194304);// 16 MB

  hipMemsetAsync(counts, 0, NE * sizeof(int), stream);
  hipMemsetAsync(out, 0, (size_t)N_TOK * NO * sizeof(float), stream);
  convert_z_kernel<<<(N_TOK * DIM / 8) / 256, 256, 0, stream>>>(z, zbf);
  router_kernel<<<N_TOK, 256, 0, stream>>>(z, rw, rb, counts, list, tkw);
  gemm1_kernel<<<GRID_G, 256, 0, stream>>>(zbf, w1, b1, counts, list, h);
  gemm2_kernel<<<GRID_G, 256, 0, stream>>>(h, w2, b2, counts, list, tkw, out);
}